// Round 7
// baseline (9240.623 us; speedup 1.0000x reference)
//
#include <hip/hip_runtime.h>
#include <stdint.h>

#define TB 8192
#define NBATCH 2
#define RES_C 512
#define SKIP_C 256
#define MEL_C 80
#define NLAYERS 30
#define XSTRIDE 9216   // TB + 2*512 zero-pad rows per batch (dilation guard)

typedef short v8s __attribute__((ext_vector_type(8)));
typedef float v4f __attribute__((ext_vector_type(4)));
typedef unsigned short v4u16 __attribute__((ext_vector_type(4)));
typedef unsigned short v8u16 __attribute__((ext_vector_type(8)));

__device__ __forceinline__ unsigned short bf16rne(float f) {
    unsigned u = __float_as_uint(f);
    return (unsigned short)((u + 0x7fffu + ((u >> 16) & 1u)) >> 16);
}
__device__ __forceinline__ float bf2f(unsigned short h) {
    return __uint_as_float((unsigned)h << 16);
}
__device__ __forceinline__ float fsigmoid(float x) { return 1.0f / (1.0f + __expf(-x)); }
__device__ __forceinline__ float ftanh_(float x) { return 2.0f / (1.0f + __expf(-2.0f * x)) - 1.0f; }

// ---------------- prep: pack weights to bf16 hi/lo, FRAGMENT order --------
// v7: one thread produces whole 16B fragment chunks -> coalesced 1KB/wave writes.
__global__ void k0_pack(const float* __restrict__ dil_w,
                        const float* __restrict__ res_w,
                        const float* __restrict__ skip_w,
                        unsigned short* __restrict__ WdH, unsigned short* __restrict__ WdL,
                        unsigned short* __restrict__ WrH, unsigned short* __restrict__ WrL,
                        unsigned short* __restrict__ WsH, unsigned short* __restrict__ WsL,
                        int split)
{
    const int Td = NLAYERS * 65536;           // (l, rt 64, ks 16, lane 64)
    const int Tr = NLAYERS * 32768;           // (l, rt 32, ks 16, lane 64)
    const int Ts = NLAYERS * 16384;           // (l, rt 16, ks 16, lane 64)
    const int total = Td + Tr + Ts;
    const int stride = gridDim.x * blockDim.x;
    for (int i = blockIdx.x * blockDim.x + threadIdx.x; i < total; i += stride) {
        if (i < Td) {
            const int lane = i & 63;
            const int blk = i >> 6;
            const int l = blk >> 10;
            const int rt = (blk >> 4) & 63;
            const int ks = blk & 15;
            const int row = rt * 16 + (lane & 15);
            const int ci = ks * 32 + (lane >> 4) * 8;
            const float* src = dil_w + ((size_t)(l * 1024 + row) * 512 + ci) * 3;
            #pragma unroll
            for (int tap = 0; tap < 3; ++tap) {
                unsigned short h8[8], l8[8];
                #pragma unroll
                for (int k = 0; k < 8; ++k) {
                    const float w = src[k * 3 + tap];
                    h8[k] = bf16rne(w);
                    l8[k] = bf16rne(w - bf2f(h8[k]));
                }
                const size_t o = (size_t)l * 1572864
                               + ((size_t)((tap * 64 + rt) * 16 + ks) << 9) + lane * 8;
                *(v8u16*)(WdH + o) = *(v8u16*)h8;
                if (split) *(v8u16*)(WdL + o) = *(v8u16*)l8;
            }
        } else if (i < Td + Tr) {
            const int j = i - Td;
            const int lane = j & 63;
            const int blk = j >> 6;
            const int l = blk >> 9;
            const int rt = (blk >> 4) & 31;
            const int ks = blk & 15;
            const int row = rt * 16 + (lane & 15);
            const int ci = ks * 32 + (lane >> 4) * 8;
            const float* src = res_w + (size_t)(l * 512 + row) * 512 + ci;
            unsigned short h8[8], l8[8];
            #pragma unroll
            for (int k = 0; k < 8; ++k) {
                const float w = src[k];
                h8[k] = bf16rne(w);
                l8[k] = bf16rne(w - bf2f(h8[k]));
            }
            const size_t o = (size_t)l * 262144 + ((size_t)(rt * 16 + ks) << 9) + lane * 8;
            *(v8u16*)(WrH + o) = *(v8u16*)h8;
            if (split) *(v8u16*)(WrL + o) = *(v8u16*)l8;
        } else {
            const int j = i - Td - Tr;
            const int lane = j & 63;
            const int blk = j >> 6;
            const int l = blk >> 8;
            const int rt = (blk >> 4) & 15;
            const int ks = blk & 15;
            const int row = rt * 16 + (lane & 15);
            const int ci = ks * 32 + (lane >> 4) * 8;
            const float* src = skip_w + (size_t)(l * 256 + row) * 512 + ci;
            unsigned short h8[8], l8[8];
            #pragma unroll
            for (int k = 0; k < 8; ++k) {
                const float w = src[k];
                h8[k] = bf16rne(w);
                l8[k] = bf16rne(w - bf2f(h8[k]));
            }
            const size_t o = (size_t)l * 131072 + ((size_t)(rt * 16 + ks) << 9) + lane * 8;
            *(v8u16*)(WsH + o) = *(v8u16*)h8;
            if (split) *(v8u16*)(WsL + o) = *(v8u16*)l8;
        }
    }
}

// ---------------- zero the dilation guard pads of xH/xL --------------------
__global__ __launch_bounds__(256)
void k_zpad(unsigned short* __restrict__ xH, unsigned short* __restrict__ xL)
{
    const int i = blockIdx.x * 256 + threadIdx.x;     // [0, 131072)
    const int row = i >> 6;                           // 2048 pad rows
    const int col = (i & 63) * 8;
    const int b = row >> 10, r = row & 1023;
    const size_t arow = (size_t)b * XSTRIDE + (r < 512 ? r : 8192 + r);
    const size_t o = (arow << 9) + col;
    *(v8u16*)(xH + o) = (v8u16)0;
    *(v8u16*)(xL + o) = (v8u16)0;
}

// ---------------- init: x0 = start_conv(audio) + mel_conv(mel) -------------
__global__ __launch_bounds__(256)
void k_init(const float* __restrict__ audio, const float* __restrict__ mel,
            const float* __restrict__ start_w, const float* __restrict__ start_b,
            const float* __restrict__ mel_w, const float* __restrict__ mel_b,
            unsigned short* __restrict__ xH, unsigned short* __restrict__ xL,
            float* __restrict__ skip_acc, int split)
{
    __shared__ float melw[32 * 84];
    __shared__ float mels[80 * 132];
    const int tid = threadIdx.x;
    const int bid = blockIdx.x;
    const int cc = bid & 15;
    const int tt = (bid >> 4) & 63;
    const int b = bid >> 10;
    const int c0 = cc * 32, t0 = tt * 128;

    for (int i = tid; i < 32 * 80; i += 256) {
        const int c = i / 80, m = i - c * 80;
        melw[c * 84 + m] = mel_w[(size_t)(c0 + c) * MEL_C + m];
    }
    for (int i = tid; i < 80 * 32; i += 256) {
        const int m = i >> 5, t4 = (i & 31) * 4;
        *(float4*)(mels + m * 132 + t4) =
            *(const float4*)(mel + ((size_t)b * MEL_C + m) * TB + t0 + t4);
    }
    __syncthreads();

    const int c = c0 + (tid & 31);
    const int tg = (tid >> 5) * 16;
    float acc[16];
    const float base = start_b[c] + mel_b[c];
    const float sw = start_w[c];
    #pragma unroll
    for (int i = 0; i < 16; ++i)
        acc[i] = fmaf(sw, audio[(size_t)b * TB + t0 + tg + i], base);
    const float* wrow = melw + (tid & 31) * 84;
    for (int m = 0; m < MEL_C; ++m) {
        const float w = wrow[m];
        const float* mr = mels + m * 132 + tg;
        #pragma unroll
        for (int i = 0; i < 16; ++i)
            acc[i] = fmaf(w, mr[i], acc[i]);
    }
    #pragma unroll
    for (int i = 0; i < 16; ++i) {
        const size_t o = ((size_t)(b * XSTRIDE + 512 + t0 + tg + i) << 9) + c;
        const unsigned short h = bf16rne(acc[i]);
        xH[o] = h;
        if (split) xL[o] = bf16rne(acc[i] - bf2f(h));
    }
    if (cc < 8) {
        const int cs = cc * 32 + (tid & 31);
        #pragma unroll
        for (int i = 0; i < 16; ++i)
            skip_acc[(size_t)(b * TB + t0 + tg + i) * SKIP_C + cs] = 0.f;
    }
}

// ---------------- K1 v7: wave = 8 channel-tiles (4f+4g) x 2 t-tiles --------
// grid 1024 = 8 p (bid&7, XCD-pinned weight slice) x 128 t-tiles of 128.
// One phase per kc(32): slab = 3 tap-windows x 128 rows staged once; all 3
// taps computed per phase -> 144 MFMAs per 12 ds_read_b128 (ratio 12:1,
// breaks the measured ~31% LDS-BW MfmaUtil cap of the 2-tile design).
__global__ __launch_bounds__(256, 2)
void k1_dilgate(const unsigned short* __restrict__ xH,
                const unsigned short* __restrict__ xL,
                unsigned short* __restrict__ aH, unsigned short* __restrict__ aL,
                const unsigned short* __restrict__ WdH,  // packed, this layer
                const unsigned short* __restrict__ WdL,
                const float* __restrict__ dil_b,         // [1024] this layer
                int dil, int split)
{
    __shared__ unsigned short shi[384 * 32];   // [tap*128+row][32], XOR-chunk swz
    __shared__ unsigned short slo[384 * 32];
    const int tid = threadIdx.x;
    const int wave = tid >> 6, lane = tid & 63;
    const int quad = lane >> 4, l15 = lane & 15;
    const int p = blockIdx.x & 7;
    const int tl = blockIdx.x >> 3;           // 0..127
    const int b = tl >> 6;
    const int t0 = (tl & 63) << 7;

    const v4f vz = {0.f, 0.f, 0.f, 0.f};
    v4f accF[4][2], accG[4][2];
    #pragma unroll
    for (int ft = 0; ft < 4; ++ft)
        #pragma unroll
        for (int n = 0; n < 2; ++n) { accF[ft][n] = vz; accG[ft][n] = vz; }

    v8u16 rH[6], rL[6];
    auto do_load = [&](int kc) {
        #pragma unroll
        for (int s = 0; s < 6; ++s) {
            const int sidx = s * 256 + tid;       // 0..1535
            const int row = sidx >> 2, chunk = sidx & 3;
            const int wrow = row & 127, tap = row >> 7;
            const int tsrc = t0 + wrow + (tap - 1) * dil;   // pad-guarded
            const size_t g = ((size_t)(b * XSTRIDE + 512 + tsrc) << 9) + kc * 32 + chunk * 8;
            rH[s] = *(const v8u16*)(xH + g);
            if (split) rL[s] = *(const v8u16*)(xL + g);
        }
    };

    do_load(0);
    #pragma unroll 1
    for (int kc = 0; kc < 16; ++kc) {
        __syncthreads();
        #pragma unroll
        for (int s = 0; s < 6; ++s) {
            const int sidx = s * 256 + tid;
            const int row = sidx >> 2, chunk = sidx & 3;
            const int swz = (chunk ^ (row & 3)) << 3;
            *(v8u16*)(shi + row * 32 + swz) = rH[s];
            if (split) *(v8u16*)(slo + row * 32 + swz) = rL[s];
        }
        __syncthreads();
        if (kc < 15) do_load(kc + 1);         // in flight during compute

        #pragma unroll 1
        for (int tap = 0; tap < 3; ++tap) {
            v8s afh[4], agh[4], afl[4], agl[4];
            #pragma unroll
            for (int ft = 0; ft < 4; ++ft) {
                const int rtf = p * 4 + ft;
                const size_t of = ((size_t)((tap * 64 + rtf) * 16 + kc) << 9) + lane * 8;
                const size_t og = ((size_t)((tap * 64 + rtf + 32) * 16 + kc) << 9) + lane * 8;
                afh[ft] = *(const v8s*)(WdH + of);
                agh[ft] = *(const v8s*)(WdH + og);
                if (split) {
                    afl[ft] = *(const v8s*)(WdL + of);
                    agl[ft] = *(const v8s*)(WdL + og);
                }
            }
            #pragma unroll
            for (int n = 0; n < 2; ++n) {
                const int toff = wave * 32 + n * 16 + l15;
                const int pos = (tap * 128 + toff) * 32 + ((quad ^ (toff & 3)) << 3);
                const v8s bh = *(const v8s*)(shi + pos);
                v8s bl;
                if (split) bl = *(const v8s*)(slo + pos);
                #pragma unroll
                for (int ft = 0; ft < 4; ++ft) {
                    accF[ft][n] = __builtin_amdgcn_mfma_f32_16x16x32_bf16(afh[ft], bh, accF[ft][n], 0, 0, 0);
                    accG[ft][n] = __builtin_amdgcn_mfma_f32_16x16x32_bf16(agh[ft], bh, accG[ft][n], 0, 0, 0);
                    if (split) {
                        accF[ft][n] = __builtin_amdgcn_mfma_f32_16x16x32_bf16(afh[ft], bl, accF[ft][n], 0, 0, 0);
                        accF[ft][n] = __builtin_amdgcn_mfma_f32_16x16x32_bf16(afl[ft], bh, accF[ft][n], 0, 0, 0);
                        accG[ft][n] = __builtin_amdgcn_mfma_f32_16x16x32_bf16(agh[ft], bl, accG[ft][n], 0, 0, 0);
                        accG[ft][n] = __builtin_amdgcn_mfma_f32_16x16x32_bf16(agl[ft], bh, accG[ft][n], 0, 0, 0);
                    }
                }
            }
        }
    }
    // gate epilogue; a written in k3's A-frag layout (coalesced 512B/wave)
    const size_t aBbase = (size_t)b * TB * 512;
    #pragma unroll
    for (int ft = 0; ft < 4; ++ft) {
        const int chq = p * 64 + ft * 16 + quad * 4;
        const int kc3 = p * 2 + (ft >> 1);
        const int chunk = ((ft & 1) << 1) + (quad >> 1);
        const int q1 = quad & 1;
        const float4 bF = *(const float4*)(dil_b + chq);
        const float4 bG = *(const float4*)(dil_b + 512 + chq);
        #pragma unroll
        for (int n = 0; n < 2; ++n) {
            const int t = t0 + wave * 32 + n * 16 + l15;
            float a0 = ftanh_(accF[ft][n][0] + bF.x) * fsigmoid(accG[ft][n][0] + bG.x);
            float a1 = ftanh_(accF[ft][n][1] + bF.y) * fsigmoid(accG[ft][n][1] + bG.y);
            float a2 = ftanh_(accF[ft][n][2] + bF.z) * fsigmoid(accG[ft][n][2] + bG.z);
            float a3 = ftanh_(accF[ft][n][3] + bF.w) * fsigmoid(accG[ft][n][3] + bG.w);
            const size_t pos = aBbase + (size_t)(t >> 4) * 8192 + kc3 * 512
                             + chunk * 128 + l15 * 8 + q1 * 4;
            v4u16 oh;
            oh[0] = bf16rne(a0); oh[1] = bf16rne(a1);
            oh[2] = bf16rne(a2); oh[3] = bf16rne(a3);
            *(v4u16*)(aH + pos) = oh;
            if (split) {
                v4u16 ol;
                ol[0] = bf16rne(a0 - bf2f(oh[0]));
                ol[1] = bf16rne(a1 - bf2f(oh[1]));
                ol[2] = bf16rne(a2 - bf2f(oh[2]));
                ol[3] = bf16rne(a3 - bf2f(oh[3]));
                *(v4u16*)(aL + pos) = ol;
            }
        }
    }
}

// ---------------- K3: x += res(a); skip += skipconv(a) ---------------------
// Barrier-free; all operands fragment-packed & coalesced (R5/R6-proven).
__global__ __launch_bounds__(256, 4)
void k3_resskip(unsigned short* __restrict__ xH, unsigned short* __restrict__ xL,
                float* __restrict__ skip_acc,
                const unsigned short* __restrict__ aH,
                const unsigned short* __restrict__ aL,
                const unsigned short* __restrict__ WrH, const unsigned short* __restrict__ WrL,
                const unsigned short* __restrict__ WsH, const unsigned short* __restrict__ WsL,
                const float* __restrict__ res_b, const float* __restrict__ skip_b,
                int split)
{
    const int tid = threadIdx.x;
    const int wave = tid >> 6, lane = tid & 63;
    const int quad = lane >> 4, l15 = lane & 15;
    const int tt = blockIdx.x & 255;
    const int bg = blockIdx.x >> 8;               // 0..2
    const int b = tt >> 7;
    const int t0 = (tt & 127) << 6;
    const int nt0 = bg * 16 + wave * 4;           // 4 n-tiles; res nt<32, skip >=32

    const v4f vz = {0.f, 0.f, 0.f, 0.f};
    v4f acc[4][4];
    #pragma unroll
    for (int mi = 0; mi < 4; ++mi)
        #pragma unroll
        for (int j = 0; j < 4; ++j) acc[mi][j] = vz;

    const size_t ab = (size_t)b * TB * 512 + lane * 8;
    const unsigned short* bHp[4];
    const unsigned short* bLp[4];
    unsigned wt[4];
    #pragma unroll
    for (int j = 0; j < 4; ++j) {
        const int nt = nt0 + j;
        if (nt < 32) { bHp[j] = WrH; bLp[j] = WrL; wt[j] = nt; }
        else         { bHp[j] = WsH; bLp[j] = WsL; wt[j] = nt - 32; }
    }

    for (int kc = 0; kc < 16; ++kc) {
        v8s ah[4], al[4];
        #pragma unroll
        for (int mi = 0; mi < 4; ++mi) {
            const size_t pos = ab + (size_t)((t0 >> 4) + mi) * 8192 + kc * 512;
            ah[mi] = *(const v8s*)(aH + pos);
            if (split) al[mi] = *(const v8s*)(aL + pos);
        }
        #pragma unroll
        for (int j = 0; j < 4; ++j) {
            const size_t wpos = ((size_t)(wt[j] * 16 + kc) << 9) + lane * 8;
            const v8s bh = *(const v8s*)(bHp[j] + wpos);
            v8s bl;
            if (split) bl = *(const v8s*)(bLp[j] + wpos);
            #pragma unroll
            for (int mi = 0; mi < 4; ++mi) {
                acc[mi][j] = __builtin_amdgcn_mfma_f32_16x16x32_bf16(ah[mi], bh, acc[mi][j], 0, 0, 0);
                if (split) {
                    acc[mi][j] = __builtin_amdgcn_mfma_f32_16x16x32_bf16(ah[mi], bl, acc[mi][j], 0, 0, 0);
                    acc[mi][j] = __builtin_amdgcn_mfma_f32_16x16x32_bf16(al[mi], bh, acc[mi][j], 0, 0, 0);
                }
            }
        }
    }

    // epilogue: col(N)=c=l15-based, row(M)=t=quad*4+r
    #pragma unroll
    for (int j = 0; j < 4; ++j) {
        const int nt = nt0 + j;
        if (nt < 32) {
            const int c = nt * 16 + l15;
            const float bias = res_b[c];
            #pragma unroll
            for (int mi = 0; mi < 4; ++mi) {
                #pragma unroll
                for (int r = 0; r < 4; ++r) {
                    const int t = t0 + mi * 16 + quad * 4 + r;
                    const size_t op = ((size_t)(b * XSTRIDE + 512 + t) << 9) + c;
                    float xv = bf2f(xH[op]);
                    if (split) xv += bf2f(xL[op]);
                    const float v = xv + acc[mi][j][r] + bias;
                    const unsigned short h = bf16rne(v);
                    xH[op] = h;
                    if (split) xL[op] = bf16rne(v - bf2f(h));
                }
            }
        } else {
            const int c2 = (nt - 32) * 16 + l15;
            const float bias = skip_b[c2];
            #pragma unroll
            for (int mi = 0; mi < 4; ++mi) {
                #pragma unroll
                for (int r = 0; r < 4; ++r) {
                    const int t = t0 + mi * 16 + quad * 4 + r;
                    const size_t o = (size_t)(b * TB + t) * SKIP_C + c2;
                    skip_acc[o] += acc[mi][j][r] + bias;
                }
            }
        }
    }
}

// ---------------- final: out = tanh(fc2(relu(fc1(skip)))) ------------------
__global__ __launch_bounds__(256)
void k4_final(const float* __restrict__ skip_acc,
              const float* __restrict__ fc1_w, const float* __restrict__ fc1_b,
              const float* __restrict__ fc2_w, const float* __restrict__ fc2_b,
              float* __restrict__ out)
{
    __shared__ float stile[32 * 260];
    __shared__ float part[8][32];
    const int tid = threadIdx.x;
    const int b = blockIdx.x >> 8;
    const int t0 = (blockIdx.x & 255) << 5;
    {
        const int r = tid >> 3, sub = tid & 7;
        const float* srow = skip_acc + (size_t)(b * TB + t0 + r) * SKIP_C;
        float* drow = stile + r * 260;
        #pragma unroll
        for (int i = 0; i < 8; ++i) {
            const int c = (i * 8 + sub) * 4;
            *(float4*)(drow + c) = *(const float4*)(srow + c);
        }
    }
    __syncthreads();
    const int t = tid & 31;
    const int w = tid >> 5;
    float y[32];
    #pragma unroll
    for (int co = 0; co < 32; ++co) y[co] = fc1_b[w * 32 + co];
    const float* srow = stile + t * 260;
    for (int ci = 0; ci < SKIP_C; ++ci) {
        const float s = srow[ci];
        const float* wcol = fc1_w + (size_t)(w * 32) * SKIP_C + ci;
        #pragma unroll
        for (int co = 0; co < 32; ++co)
            y[co] = fmaf(wcol[(size_t)co * SKIP_C], s, y[co]);
    }
    float partial = 0.f;
    #pragma unroll
    for (int co = 0; co < 32; ++co) {
        const float v = y[co] > 0.f ? y[co] : 0.f;
        partial = fmaf(fc2_w[w * 32 + co], v, partial);
    }
    part[w][t] = partial;
    __syncthreads();
    if (tid < 32) {
        float v = fc2_b[0];
        #pragma unroll
        for (int k = 0; k < 8; ++k) v += part[k][tid];
        out[(size_t)b * TB + t0 + tid] = ftanh_(v);
    }
}

// ---------------- host ----------------
extern "C" void kernel_launch(void* const* d_in, const int* in_sizes, int n_in,
                              void* d_out, int out_size, void* d_ws, size_t ws_size,
                              hipStream_t stream)
{
    const float* mel     = (const float*)d_in[0];
    const float* audio   = (const float*)d_in[1];
    const float* start_w = (const float*)d_in[2];
    const float* start_b = (const float*)d_in[3];
    const float* mel_w   = (const float*)d_in[4];
    const float* mel_b   = (const float*)d_in[5];
    const float* dil_b   = (const float*)d_in[7];
    const float* res_b   = (const float*)d_in[9];
    const float* skip_b  = (const float*)d_in[11];
    const float* fc1_w   = (const float*)d_in[12];
    const float* fc1_b   = (const float*)d_in[13];
    const float* fc2_w   = (const float*)d_in[14];
    const float* fc2_b   = (const float*)d_in[15];
    float* out = (float*)d_out;

    char* ws = (char*)d_ws;
    const size_t szWd  = (size_t)NLAYERS * 3 * 1024 * 512 * 2;
    const size_t szWr  = (size_t)NLAYERS * 512 * 512 * 2;
    const size_t szWs  = (size_t)NLAYERS * 256 * 512 * 2;
    const size_t szXp  = (size_t)NBATCH * XSTRIDE * RES_C * 2;
    const size_t szA16 = (size_t)NBATCH * TB * RES_C * 2;
    const size_t szSk  = (size_t)NBATCH * TB * SKIP_C * 4;
    size_t off = 0;
    unsigned short* WdH = (unsigned short*)(ws + off); off += szWd;
    unsigned short* WrH = (unsigned short*)(ws + off); off += szWr;
    unsigned short* WsH = (unsigned short*)(ws + off); off += szWs;
    unsigned short* xH  = (unsigned short*)(ws + off); off += szXp;
    unsigned short* aH  = (unsigned short*)(ws + off); off += szA16;
    float* skip_acc     = (float*)(ws + off);          off += szSk;
    const size_t lo_need = szXp + szA16 + szWd + szWr + szWs;
    const int split = (off + lo_need <= ws_size) ? 1 : 0;
    unsigned short* xL  = split ? (unsigned short*)(ws + off) : xH; if (split) off += szXp;
    unsigned short* aL  = split ? (unsigned short*)(ws + off) : aH; if (split) off += szA16;
    unsigned short* WdL = split ? (unsigned short*)(ws + off) : WdH; if (split) off += szWd;
    unsigned short* WrL = split ? (unsigned short*)(ws + off) : WrH; if (split) off += szWr;
    unsigned short* WsL = split ? (unsigned short*)(ws + off) : WsH; if (split) off += szWs;

    k0_pack<<<8192, 256, 0, stream>>>((const float*)d_in[6], (const float*)d_in[8],
                                      (const float*)d_in[10],
                                      WdH, WdL, WrH, WrL, WsH, WsL, split);
    k_zpad<<<512, 256, 0, stream>>>(xH, xL);
    k_init<<<2048, 256, 0, stream>>>(
        audio, mel, start_w, start_b, mel_w, mel_b, xH, xL, skip_acc, split);

    for (int l = 0; l < NLAYERS; ++l) {
        const int dil = 1 << (l % 10);
        k1_dilgate<<<1024, 256, 0, stream>>>(xH, xL, aH, aL,
            WdH + (size_t)l * 1572864, WdL + (size_t)l * 1572864,
            dil_b + (size_t)l * 1024, dil, split);
        k3_resskip<<<768, 256, 0, stream>>>(xH, xL, skip_acc, aH, aL,
            WrH + (size_t)l * 262144, WrL + (size_t)l * 262144,
            WsH + (size_t)l * 131072, WsL + (size_t)l * 131072,
            res_b + (size_t)l * 512, skip_b + (size_t)l * 256, split);
    }
    k4_final<<<512, 256, 0, stream>>>(skip_acc, fc1_w, fc1_b, fc2_w, fc2_b, out);
}